// Round 16
// baseline (135.048 us; speedup 1.0000x reference)
//
#include <hip/hip_runtime.h>
#include <math.h>

#define DD   256   // feature dim
#define NN   128   // neighbors
#define NB   572   // drugs
#define NREL 100   // distinct relation rows
#define KS   32    // k-step (MFMA K)
#define NKS  (DD / KS)
#define EQ   64    // e-quarter per mm block
#define RS   80    // LDS row stride in halves (160B; 40 words == 8 mod 32)
#define PSS  68    // P scratch stride (f32)
#define LDRUGS 8

typedef _Float16 h8 __attribute__((ext_vector_type(8)));
typedef float    f4 __attribute__((ext_vector_type(4)));

__device__ __forceinline__ float4 ld4(const float* p) {
    return *reinterpret_cast<const float4*>(p);
}
__device__ __forceinline__ void split16(float x, _Float16& hi, _Float16& lo) {
    hi = (_Float16)x;
    lo = (_Float16)(x - (float)hi);
}
// XOR slot swizzle: blk2 = 2*k_octet + hilo (0..7); returns halves offset
__device__ __forceinline__ int slotx(int blk2, int row) {
    return ((blk2 ^ (row & 7)) & 7) * 8;
}

// ---------------------------------------------------------------------------
// Kernel 1: streaming row-sums (BW-bound). blocks 0..2NB-1: W2[b] row-half.
// block 2NB: b2 row-sums.
// ---------------------------------------------------------------------------
__global__ __launch_bounds__(256)
void sum_rows(const float* __restrict__ W2, const float* __restrict__ b2,
              float* __restrict__ w2s, float* __restrict__ b2s)
{
    const int blk  = blockIdx.x;
    const int tid  = threadIdx.x;
    const int lane = tid & 63;
    const int wv   = tid >> 6;

    if (blk < 2 * NB) {
        const int b = blk >> 1, half = blk & 1;
        const float* src = W2 + (size_t)b * DD * DD + (size_t)half * (DD / 2) * DD;
        float* dst = w2s + (size_t)b * DD + half * (DD / 2);
        for (int r = wv; r < DD / 2; r += 4) {
            float4 v = ld4(&src[r * DD + lane * 4]);
            float s = v.x + v.y + v.z + v.w;
            #pragma unroll
            for (int m = 32; m >= 1; m >>= 1) s += __shfl_xor(s, m, 64);
            if (lane == 0) dst[r] = s;
        }
    } else {
        for (int r = wv; r < NN; r += 4) {
            float4 v = ld4(&b2[r * DD + lane * 4]);
            float s = v.x + v.y + v.z + v.w;
            #pragma unroll
            for (int m = 32; m >= 1; m >>= 1) s += __shfl_xor(s, m, 64);
            if (lane == 0) b2s[r] = s;
        }
    }
}

// ---------------------------------------------------------------------------
// Kernel 2: MFMA matmul + partial logits. Block = (drug b, e-quarter q).
// 256 threads / 4 waves (2 rg x 2 cg of 32 cols). f16 hi/lo 3-product;
// single-buffer XOR-swizzled LDS; h8-only writes; 2 barriers per k-step.
// part[b, q*128... ] : part[(b*4+q)*128 + n] = sum_{e in quarter} relu(...)·w2s
// ---------------------------------------------------------------------------
__global__ __launch_bounds__(256, 4)
void gnn_mm(const float* __restrict__ drug_table,
            const float* __restrict__ rela_table,
            const float* __restrict__ W1,
            const float* __restrict__ b1,
            const int*   __restrict__ drug_name,
            const int*   __restrict__ adj_relation,
            const float* __restrict__ w2s_g,
            float* __restrict__ part)
{
    __shared__ __align__(16) _Float16 AB_l[(128 + EQ) * RS];  // A | B, 30 KB
    __shared__ float d_l[DD];
    __shared__ float w2s_l[EQ];
    __shared__ int   rel_l[NN], urel_l[NN], head_l[NN], next_l[NN];
    __shared__ int   map_l[NREL];
    __shared__ int   U_l, c0_l;

    _Float16* A_l = AB_l;
    _Float16* B_l = AB_l + 128 * RS;
    float*    Pl  = reinterpret_cast<float*>(AB_l);   // 32 x 68 f32 overlay

    const int bid  = blockIdx.x;
    const int b    = bid >> 2, q = bid & 3;
    const int tid  = threadIdx.x;
    const int lane = tid & 63;
    const int wv   = tid >> 6;          // 0..3
    const int rg   = wv >> 1;           // 0..1
    const int cg   = wv & 1;            // 0..1 (32 e each)
    const int r16  = lane & 15;
    const int gb   = lane >> 4;         // k-octet 0..3

    // ---- setup ----
    if (tid < NN) { rel_l[tid] = adj_relation[b * NN + tid]; head_l[tid] = -1; }
    if (tid < NREL) map_l[tid] = -1;
    d_l[tid] = drug_table[(size_t)drug_name[b] * DD + tid];
    if (tid >= 192) w2s_l[tid - 192] = w2s_g[(size_t)b * DD + q * EQ + (tid - 192)];
    __syncthreads();
    if (tid < NN) map_l[rel_l[tid]] = 1;
    __syncthreads();

    // ---- ballot compaction of <=100 marked relations ----
    bool mk = false; int rank = 0, tot = 0;
    if (tid < 128) {
        mk = (tid < NREL) && (map_l[tid] != -1);
        unsigned long long bal = __ballot(mk);
        rank = __popcll(bal & ((1ull << (tid & 63)) - 1));
        tot  = __popcll(bal);
    }
    if (tid < 64) {
        if (mk) { map_l[tid] = rank; urel_l[rank] = tid; }
        if (tid == 0) c0_l = tot;
    }
    __syncthreads();
    if (tid >= 64 && tid < 128) {
        const int base = c0_l;
        if (mk) { map_l[tid] = base + rank; urel_l[base + rank] = tid; }
        if (tid == 64) U_l = base + tot;
    }
    __syncthreads();
    if (tid < NN)
        next_l[tid] = atomicExch(&head_l[map_l[rel_l[tid]]], tid);
    __syncthreads();

    const int U   = U_l;
    const int NRT = (U + 31) >> 5;

    const float* W1b = W1 + (size_t)b * DD * DD;

    // ---- zero-pad A rows U..NRT*32-1 (data halves [0,64)) ----
    {
        const int padrows = NRT * 32 - U;
        h8 z = {(_Float16)0.f,(_Float16)0.f,(_Float16)0.f,(_Float16)0.f,
                (_Float16)0.f,(_Float16)0.f,(_Float16)0.f,(_Float16)0.f};
        for (int x = tid; x < padrows * 8; x += 256) {
            int r = U + (x >> 3), c = (x & 7) * 8;
            *(h8*)&A_l[r * RS + c] = z;
        }
    }

    // staging maps (h8-only LDS writes)
    const int kb  = tid >> 6;           // B: k-octet 0..3
    const int be  = tid & 63;           // B: e column 0..63
    const int sau = tid >> 1;           // A: u row 0..127
    const int sa2 = (tid & 1) * 2;      // A: first of 2 k-octets

    float rbv[8];
    float4 raA, raB, raC, raD;

    #define STAGE_LOAD(kt_) {                                                  \
        const int k0_ = (kt_) * KS + kb * 8;                                   \
        const float* wp = &W1b[(size_t)k0_ * DD + q * EQ + be];                \
        _Pragma("unroll")                                                      \
        for (int j = 0; j < 8; ++j) rbv[j] = wp[(size_t)j * DD];               \
        if (sau < U) {                                                         \
            const float* rr = rela_table + (size_t)urel_l[sau] * DD            \
                              + (kt_) * KS + sa2 * 8;                          \
            raA = ld4(rr);     raB = ld4(rr + 4);                              \
            raC = ld4(rr + 8); raD = ld4(rr + 12);                             \
        }                                                                      \
    }

    #define STAGE_WRITE(kt_) {                                                 \
        const int k0_ = (kt_) * KS + kb * 8;                                   \
        h8 hv, lv;                                                             \
        _Pragma("unroll")                                                      \
        for (int j = 0; j < 8; ++j) {                                          \
            _Float16 hh, ll;                                                   \
            split16(rbv[j] * d_l[k0_ + j], hh, ll);                            \
            hv[j] = hh; lv[j] = ll;                                            \
        }                                                                      \
        *(h8*)&B_l[be * RS + slotx(2 * kb,     be)] = hv;                      \
        *(h8*)&B_l[be * RS + slotx(2 * kb + 1, be)] = lv;                      \
        if (sau < U) {                                                         \
            const float vr[16] = {raA.x, raA.y, raA.z, raA.w,                  \
                                  raB.x, raB.y, raB.z, raB.w,                  \
                                  raC.x, raC.y, raC.z, raC.w,                  \
                                  raD.x, raD.y, raD.z, raD.w};                 \
            _Pragma("unroll")                                                  \
            for (int o = 0; o < 2; ++o) {                                      \
                const int oct = sa2 + o;                                       \
                h8 ahv, alv;                                                   \
                _Pragma("unroll")                                              \
                for (int j = 0; j < 8; ++j) {                                  \
                    _Float16 hh, ll;                                           \
                    split16(vr[o * 8 + j], hh, ll);                            \
                    ahv[j] = hh; alv[j] = ll;                                  \
                }                                                              \
                *(h8*)&A_l[sau * RS + slotx(2 * oct,     sau)] = ahv;          \
                *(h8*)&A_l[sau * RS + slotx(2 * oct + 1, sau)] = alv;          \
            }                                                                  \
        }                                                                      \
    }

    STAGE_LOAD(0);
    STAGE_WRITE(0);
    __syncthreads();

    f4 acc[2][2][2];   // [p][sr][sc]
    #pragma unroll
    for (int p = 0; p < 2; ++p)
        #pragma unroll
        for (int sr = 0; sr < 2; ++sr)
            #pragma unroll
            for (int sc = 0; sc < 2; ++sc)
                acc[p][sr][sc] = {0.f, 0.f, 0.f, 0.f};

    // ---- k-loop ----
    for (int kt = 0; kt < NKS; ++kt) {
        if (kt + 1 < NKS) STAGE_LOAD(kt + 1);

        h8 bh[2], bl[2];
        #pragma unroll
        for (int sc = 0; sc < 2; ++sc) {
            const int e = cg * 32 + sc * 16 + r16;
            bh[sc] = *(const h8*)&B_l[e * RS + slotx(2 * gb,     e)];
            bl[sc] = *(const h8*)&B_l[e * RS + slotx(2 * gb + 1, e)];
        }
        #pragma unroll
        for (int p = 0; p < 2; ++p) {
            const int rt = rg + 2 * p;
            if (rt < NRT) {
                #pragma unroll
                for (int sr = 0; sr < 2; ++sr) {
                    const int row = rt * 32 + sr * 16 + r16;
                    h8 ah = *(const h8*)&A_l[row * RS + slotx(2 * gb,     row)];
                    h8 al = *(const h8*)&A_l[row * RS + slotx(2 * gb + 1, row)];
                    #pragma unroll
                    for (int sc = 0; sc < 2; ++sc) {
                        acc[p][sr][sc] = __builtin_amdgcn_mfma_f32_16x16x32_f16(ah, bh[sc], acc[p][sr][sc], 0, 0, 0);
                        acc[p][sr][sc] = __builtin_amdgcn_mfma_f32_16x16x32_f16(al, bh[sc], acc[p][sr][sc], 0, 0, 0);
                        acc[p][sr][sc] = __builtin_amdgcn_mfma_f32_16x16x32_f16(ah, bl[sc], acc[p][sr][sc], 0, 0, 0);
                    }
                }
            }
        }
        __syncthreads();                 // all reads of tile kt done
        if (kt + 1 < NKS) STAGE_WRITE(kt + 1);
        __syncthreads();                 // tile kt+1 visible
    }
    #undef STAGE_LOAD
    #undef STAGE_WRITE

    // ---- epilogue: per row-tile, acc -> P (overlays arena) -> partial logits
    const int ug  = tid >> 3;           // 0..31
    const int td8 = tid & 7;
    float4 w0  = ld4(&w2s_l[td8 * 8]);
    float4 w1v = ld4(&w2s_l[td8 * 8 + 4]);

    for (int rt = 0; rt < 4; ++rt) {
        if (rt < NRT) {
            __syncthreads();
            if ((rt & 1) == rg) {
                const int p = rt >> 1;
                #pragma unroll
                for (int sr = 0; sr < 2; ++sr)
                    #pragma unroll
                    for (int sc = 0; sc < 2; ++sc)
                        #pragma unroll
                        for (int jj = 0; jj < 4; ++jj)
                            Pl[(sr * 16 + gb * 4 + jj) * PSS + cg * 32 + sc * 16 + r16] =
                                acc[p][sr][sc][jj];
            }
            __syncthreads();
            const int u = rt * 32 + ug;
            if (u < U) {
                float4 p0 = ld4(&Pl[ug * PSS + td8 * 8]);
                float4 p1 = ld4(&Pl[ug * PSS + td8 * 8 + 4]);
                int n = head_l[u];
                while (n >= 0) {
                    const float* bp = b1 + (size_t)n * DD + q * EQ + td8 * 8;
                    float4 b0 = ld4(bp);
                    float4 b1v = ld4(bp + 4);
                    float s = fmaxf(p0.x + b0.x,  0.f) * w0.x
                            + fmaxf(p0.y + b0.y,  0.f) * w0.y
                            + fmaxf(p0.z + b0.z,  0.f) * w0.z
                            + fmaxf(p0.w + b0.w,  0.f) * w0.w
                            + fmaxf(p1.x + b1v.x, 0.f) * w1v.x
                            + fmaxf(p1.y + b1v.y, 0.f) * w1v.y
                            + fmaxf(p1.z + b1v.z, 0.f) * w1v.z
                            + fmaxf(p1.w + b1v.w, 0.f) * w1v.w;
                    #pragma unroll
                    for (int m = 4; m >= 1; m >>= 1) s += __shfl_xor(s, m, 8);
                    if (td8 == 0) part[(size_t)(b * 4 + q) * NN + n] = s;
                    n = next_l[n];
                }
            }
        }
    }
}

// ---------------------------------------------------------------------------
// Kernel 3: per drug — combine partials (+b2s), softmax, sparse ent gather
// ---------------------------------------------------------------------------
__global__ __launch_bounds__(256)
void gnn_gather(const float* __restrict__ drug_table,
                const float* __restrict__ ent_table,
                const int*   __restrict__ drug_name,
                const int*   __restrict__ adj_tail,
                const float* __restrict__ part,
                const float* __restrict__ b2s_g,
                float* __restrict__ xbuf)
{
    __shared__ float score_l[NN];
    __shared__ int   tail_l[NN];

    const int b = blockIdx.x, tid = threadIdx.x;

    if (tid < NN) {
        tail_l[tid]  = adj_tail[b * NN + tid];
        const float* pp = part + (size_t)b * 4 * NN + tid;
        score_l[tid] = pp[0] + pp[NN] + pp[2 * NN] + pp[3 * NN] + b2s_g[tid];
    }
    __syncthreads();

    if (tid < 64) {
        float l0 = score_l[tid], l1 = score_l[tid + 64];
        float M = fmaxf(l0, l1);
        #pragma unroll
        for (int m = 32; m >= 1; m >>= 1) M = fmaxf(M, __shfl_xor(M, m, 64));
        float e0 = expf(l0 - M), e1 = expf(l1 - M);
        float S = e0 + e1;
        #pragma unroll
        for (int m = 32; m >= 1; m >>= 1) S += __shfl_xor(S, m, 64);
        float inv = 1.f / S;
        score_l[tid]      = e0 * inv;
        score_l[tid + 64] = e1 * inv;
    }
    __syncthreads();

    // sparse gather (softmax ~one-hot; skipped mass < 1.3e-7)
    float w = 0.f;
    for (int n = 0; n < NN; ++n) {
        float s = score_l[n];
        if (s > 1e-9f)
            w = fmaf(s, ent_table[(size_t)tail_l[n] * DD + tid], w);
    }
    xbuf[(size_t)b * 512 + tid]       = w;
    xbuf[(size_t)b * 512 + 256 + tid] = drug_table[(size_t)drug_name[b] * DD + tid];
}

// ---------------------------------------------------------------------------
// Kernel 4: batched linear
// ---------------------------------------------------------------------------
__global__ __launch_bounds__(256)
void gnn_lin(const float* __restrict__ lin_w,
             const float* __restrict__ lin_b,
             const float* __restrict__ xbuf,
             float* __restrict__ Y)
{
    __shared__ float x_l[LDRUGS * 512];

    const int g = blockIdx.x, tid = threadIdx.x;
    const int b0 = g * LDRUGS;

    #pragma unroll
    for (int i = 0; i < LDRUGS * 2; ++i) {
        int f = tid + i * 256;
        *reinterpret_cast<float4*>(&x_l[f * 4]) = ld4(&xbuf[(size_t)b0 * 512 + f * 4]);
    }
    __syncthreads();

    const float* lw = lin_w + (size_t)tid * 512;
    float dot[LDRUGS];
    #pragma unroll
    for (int d = 0; d < LDRUGS; ++d) dot[d] = 0.f;

    for (int k4 = 0; k4 < 128; ++k4) {
        float4 wv = ld4(&lw[k4 * 4]);
        #pragma unroll
        for (int d = 0; d < LDRUGS; ++d) {
            float4 xv = ld4(&x_l[d * 512 + k4 * 4]);
            dot[d] += wv.x * xv.x + wv.y * xv.y + wv.z * xv.z + wv.w * xv.w;
        }
    }

    const float bb = lin_b[tid];
    #pragma unroll
    for (int d = 0; d < LDRUGS; ++d) {
        if (b0 + d < NB)
            Y[(size_t)(b0 + d) * DD + tid] = fmaxf(dot[d] + bb, 0.f);
    }
}

// ---------------------------------------------------------------------------
// Kernel 5: BN stats (deterministic fixed-order reduction) + apply
// ---------------------------------------------------------------------------
__global__ void bn_stats(const float* __restrict__ Y, float* __restrict__ stats)
{
    int d = blockIdx.x, t = threadIdx.x;   // 256 blocks x 64 threads
    float s = 0.f, ss = 0.f;
    for (int b = t; b < NB; b += 64) {
        float v = Y[(size_t)b * DD + d];
        s += v; ss += v * v;
    }
    #pragma unroll
    for (int m = 32; m >= 1; m >>= 1) {
        s  += __shfl_xor(s, m, 64);
        ss += __shfl_xor(ss, m, 64);
    }
    if (t == 0) {
        float mean = s * (1.f / NB);
        float var  = ss * (1.f / NB) - mean * mean;
        stats[d]      = mean;
        stats[DD + d] = rsqrtf(var + 1e-5f);
    }
}

__global__ void bn_apply(float* __restrict__ Y, const float* __restrict__ stats,
                         const float* __restrict__ gamma, const float* __restrict__ beta)
{
    int b = blockIdx.x, t = threadIdx.x;
    float mean = stats[t], inv = stats[DD + t];
    float v = Y[(size_t)b * DD + t];
    Y[(size_t)b * DD + t] = gamma[t] * (v - mean) * inv + beta[t];
}

extern "C" void kernel_launch(void* const* d_in, const int* in_sizes, int n_in,
                              void* d_out, int out_size, void* d_ws, size_t ws_size,
                              hipStream_t stream)
{
    const float* drug_table = (const float*)d_in[0];
    const float* rela_table = (const float*)d_in[1];
    const float* ent_table  = (const float*)d_in[2];
    const float* W1         = (const float*)d_in[3];
    const float* b1         = (const float*)d_in[4];
    const float* W2         = (const float*)d_in[5];
    const float* b2         = (const float*)d_in[6];
    const float* lin_w      = (const float*)d_in[7];
    const float* lin_b      = (const float*)d_in[8];
    const float* bn_g       = (const float*)d_in[9];
    const float* bn_b       = (const float*)d_in[10];
    const int*   drug_name  = (const int*)d_in[11];
    const int*   adj_tail   = (const int*)d_in[12];
    const int*   adj_rel    = (const int*)d_in[13];
    float* out = (float*)d_out;

    const int NBP = ((NB + LDRUGS - 1) / LDRUGS) * LDRUGS;   // 576
    float* w2s   = (float*)d_ws;                   // NB*DD
    float* b2s   = w2s + (size_t)NB * DD;          // NN
    float* part  = b2s + NN;                       // NB*4*NN
    float* xbuf  = part + (size_t)NB * 4 * NN;     // NBP*512
    float* stats = xbuf + (size_t)NBP * 512;       // 2*DD

    sum_rows<<<2 * NB + 1, 256, 0, stream>>>(W2, b2, w2s, b2s);
    gnn_mm<<<4 * NB, 256, 0, stream>>>(drug_table, rela_table, W1, b1,
                                       drug_name, adj_rel, w2s, part);
    gnn_gather<<<NB, 256, 0, stream>>>(drug_table, ent_table, drug_name,
                                       adj_tail, part, b2s, xbuf);
    gnn_lin<<<NBP / LDRUGS, 256, 0, stream>>>(lin_w, lin_b, xbuf, out);
    bn_stats<<<DD, 64, 0, stream>>>(out, stats);
    bn_apply<<<NB, DD, 0, stream>>>(out, stats, bn_g, bn_b);
}

// Round 17
// 130.465 us; speedup vs baseline: 1.0351x; 1.0351x over previous
//
#include <hip/hip_runtime.h>
#include <math.h>

#define DD   256   // feature dim
#define NN   128   // neighbors
#define NB   572   // drugs
#define NREL 100   // distinct relation rows
#define KS   32    // k-step (MFMA K)
#define NKS  (DD / KS)
#define EH   128   // e-half per mm block
#define RS   80    // LDS row stride in halves (160B; 40 words == 8 mod 32)
#define PSS  132   // P scratch stride (f32)
#define LDRUGS 8

typedef _Float16 h8 __attribute__((ext_vector_type(8)));
typedef float    f4 __attribute__((ext_vector_type(4)));

__device__ __forceinline__ float4 ld4(const float* p) {
    return *reinterpret_cast<const float4*>(p);
}
__device__ __forceinline__ void split16(float x, _Float16& hi, _Float16& lo) {
    hi = (_Float16)x;
    lo = (_Float16)(x - (float)hi);
}
// XOR slot swizzle: blk2 = 2*k_octet + hilo (0..7); returns halves offset
__device__ __forceinline__ int slotx(int blk2, int row) {
    return ((blk2 ^ (row & 7)) & 7) * 8;
}

// ---------------------------------------------------------------------------
// Kernel 1: streaming row-sums (BW-bound). blocks 0..2NB-1: W2[b] row-half.
// block 2NB: b2 row-sums.
// ---------------------------------------------------------------------------
__global__ __launch_bounds__(256)
void sum_rows(const float* __restrict__ W2, const float* __restrict__ b2,
              float* __restrict__ w2s, float* __restrict__ b2s)
{
    const int blk  = blockIdx.x;
    const int tid  = threadIdx.x;
    const int lane = tid & 63;
    const int wv   = tid >> 6;

    if (blk < 2 * NB) {
        const int b = blk >> 1, half = blk & 1;
        const float* src = W2 + (size_t)b * DD * DD + (size_t)half * (DD / 2) * DD;
        float* dst = w2s + (size_t)b * DD + half * (DD / 2);
        for (int r = wv; r < DD / 2; r += 4) {
            float4 v = ld4(&src[r * DD + lane * 4]);
            float s = v.x + v.y + v.z + v.w;
            #pragma unroll
            for (int m = 32; m >= 1; m >>= 1) s += __shfl_xor(s, m, 64);
            if (lane == 0) dst[r] = s;
        }
    } else {
        for (int r = wv; r < NN; r += 4) {
            float4 v = ld4(&b2[r * DD + lane * 4]);
            float s = v.x + v.y + v.z + v.w;
            #pragma unroll
            for (int m = 32; m >= 1; m >>= 1) s += __shfl_xor(s, m, 64);
            if (lane == 0) b2s[r] = s;
        }
    }
}

// ---------------------------------------------------------------------------
// Kernel 2: MFMA matmul + partial logits. Block = (drug b, e-half h).
// 512 threads / 8 waves (2 rg x 4 cg). f16 hi/lo 3-product;
// single-buffer XOR-swizzled LDS; h8-only writes; 2-DEEP register pipeline
// (LOAD(kt+2) issued before COMPUTE(kt), consumed end of step kt+1).
// part[b, h*128+n] = sum_{e in half} relu(P[u(n),e] + b1[n,e]) * w2s[b,e]
// ---------------------------------------------------------------------------
__global__ __launch_bounds__(512, 4)
void gnn_mm(const float* __restrict__ drug_table,
            const float* __restrict__ rela_table,
            const float* __restrict__ W1,
            const float* __restrict__ b1,
            const int*   __restrict__ drug_name,
            const int*   __restrict__ adj_relation,
            const float* __restrict__ w2s_g,
            float* __restrict__ part)
{
    __shared__ __align__(16) _Float16 AB_l[2 * 128 * RS];  // A | B, 40 KB
    __shared__ float d_l[DD];
    __shared__ float w2s_l[EH];
    __shared__ int   rel_l[NN], urel_l[NN], head_l[NN], next_l[NN];
    __shared__ int   map_l[NREL];
    __shared__ int   U_l, c0_l;

    _Float16* A_l = AB_l;
    _Float16* B_l = AB_l + 128 * RS;
    float*    Pl  = reinterpret_cast<float*>(AB_l);   // 32 x 132 f32 overlay

    const int bid  = blockIdx.x;
    const int b    = bid >> 1, h = bid & 1;
    const int tid  = threadIdx.x;
    const int lane = tid & 63;
    const int wv   = tid >> 6;          // 0..7
    const int rg   = wv >> 2;           // 0..1
    const int cg   = wv & 3;            // 0..3 (32 e each)
    const int r16  = lane & 15;
    const int gb   = lane >> 4;         // k-octet 0..3

    // ---- setup ----
    if (tid < NN) { rel_l[tid] = adj_relation[b * NN + tid]; head_l[tid] = -1; }
    if (tid < NREL) map_l[tid] = -1;
    if (tid < DD)  d_l[tid] = drug_table[(size_t)drug_name[b] * DD + tid];
    if (tid >= DD && tid < DD + EH)
        w2s_l[tid - DD] = w2s_g[(size_t)b * DD + h * EH + (tid - DD)];
    __syncthreads();
    if (tid < NN) map_l[rel_l[tid]] = 1;
    __syncthreads();

    // ---- ballot compaction of <=100 marked relations ----
    bool mk = false; int rank = 0, tot = 0;
    if (tid < 128) {
        mk = (tid < NREL) && (map_l[tid] != -1);
        unsigned long long bal = __ballot(mk);
        rank = __popcll(bal & ((1ull << (tid & 63)) - 1));
        tot  = __popcll(bal);
    }
    if (tid < 64) {
        if (mk) { map_l[tid] = rank; urel_l[rank] = tid; }
        if (tid == 0) c0_l = tot;
    }
    __syncthreads();
    if (tid >= 64 && tid < 128) {
        const int base = c0_l;
        if (mk) { map_l[tid] = base + rank; urel_l[base + rank] = tid; }
        if (tid == 64) U_l = base + tot;
    }
    __syncthreads();
    if (tid < NN)
        next_l[tid] = atomicExch(&head_l[map_l[rel_l[tid]]], tid);
    __syncthreads();

    const int U   = U_l;
    const int NRT = (U + 31) >> 5;

    const float* W1b = W1 + (size_t)b * DD * DD;

    // ---- zero-pad A rows U..NRT*32-1 (data halves [0,64)) ----
    {
        const int padrows = NRT * 32 - U;
        h8 z = {(_Float16)0.f,(_Float16)0.f,(_Float16)0.f,(_Float16)0.f,
                (_Float16)0.f,(_Float16)0.f,(_Float16)0.f,(_Float16)0.f};
        for (int x = tid; x < padrows * 8; x += 512) {
            int r = U + (x >> 3), c = (x & 7) * 8;
            *(h8*)&A_l[r * RS + c] = z;
        }
    }

    // staging maps (h8-only LDS writes)
    const int kb  = (tid >> 7) & 3;     // B: k-octet 0..3
    const int be  = tid & 127;          // B: e column
    const int sau = tid >> 2;           // A: u row 0..127
    const int sab = tid & 3;            // A: k-octet 0..3

    // two named register sets (2-deep pipeline; compile-time selection only)
    float rbvA[8], rbvB[8];
    float4 raA1, raA2, raB1, raB2;

    #define STAGE_LOAD(kt_, RB, RA1, RA2) {                                    \
        const int k0_ = (kt_) * KS + kb * 8;                                   \
        const float* wp = &W1b[(size_t)k0_ * DD + h * EH + be];                \
        _Pragma("unroll")                                                      \
        for (int j = 0; j < 8; ++j) RB[j] = wp[(size_t)j * DD];                \
        if (sau < U) {                                                         \
            const float* rr = rela_table + (size_t)urel_l[sau] * DD            \
                              + (kt_) * KS + sab * 8;                          \
            RA1 = ld4(rr); RA2 = ld4(rr + 4);                                  \
        }                                                                      \
    }

    #define STAGE_WRITE(kt_, RB, RA1, RA2) {                                   \
        const int k0_ = (kt_) * KS + kb * 8;                                   \
        h8 hv, lv;                                                             \
        _Pragma("unroll")                                                      \
        for (int j = 0; j < 8; ++j) {                                          \
            _Float16 hh, ll;                                                   \
            split16(RB[j] * d_l[k0_ + j], hh, ll);                             \
            hv[j] = hh; lv[j] = ll;                                            \
        }                                                                      \
        *(h8*)&B_l[be * RS + slotx(2 * kb,     be)] = hv;                      \
        *(h8*)&B_l[be * RS + slotx(2 * kb + 1, be)] = lv;                      \
        if (sau < U) {                                                         \
            const float vr[8] = {RA1.x, RA1.y, RA1.z, RA1.w,                   \
                                 RA2.x, RA2.y, RA2.z, RA2.w};                  \
            h8 ahv, alv;                                                       \
            _Pragma("unroll")                                                  \
            for (int j = 0; j < 8; ++j) {                                      \
                _Float16 hh, ll;                                               \
                split16(vr[j], hh, ll);                                        \
                ahv[j] = hh; alv[j] = ll;                                      \
            }                                                                  \
            *(h8*)&A_l[sau * RS + slotx(2 * sab,     sau)] = ahv;              \
            *(h8*)&A_l[sau * RS + slotx(2 * sab + 1, sau)] = alv;              \
        }                                                                      \
    }

    f4 acc[2][2][2];   // [p][sr][sc]
    #pragma unroll
    for (int p = 0; p < 2; ++p)
        #pragma unroll
        for (int sr = 0; sr < 2; ++sr)
            #pragma unroll
            for (int sc = 0; sc < 2; ++sc)
                acc[p][sr][sc] = {0.f, 0.f, 0.f, 0.f};

    #define COMPUTE() {                                                        \
        h8 bh[2], bl[2];                                                       \
        _Pragma("unroll")                                                      \
        for (int sc = 0; sc < 2; ++sc) {                                       \
            const int e = cg * 32 + sc * 16 + r16;                             \
            bh[sc] = *(const h8*)&B_l[e * RS + slotx(2 * gb,     e)];          \
            bl[sc] = *(const h8*)&B_l[e * RS + slotx(2 * gb + 1, e)];          \
        }                                                                      \
        _Pragma("unroll")                                                      \
        for (int p = 0; p < 2; ++p) {                                          \
            const int rt = rg + 2 * p;                                         \
            if (rt < NRT) {                                                    \
                _Pragma("unroll")                                              \
                for (int sr = 0; sr < 2; ++sr) {                               \
                    const int row = rt * 32 + sr * 16 + r16;                   \
                    h8 ah = *(const h8*)&A_l[row * RS + slotx(2 * gb,     row)];\
                    h8 al = *(const h8*)&A_l[row * RS + slotx(2 * gb + 1, row)];\
                    _Pragma("unroll")                                          \
                    for (int sc = 0; sc < 2; ++sc) {                           \
                        acc[p][sr][sc] = __builtin_amdgcn_mfma_f32_16x16x32_f16(ah, bh[sc], acc[p][sr][sc], 0, 0, 0);\
                        acc[p][sr][sc] = __builtin_amdgcn_mfma_f32_16x16x32_f16(al, bh[sc], acc[p][sr][sc], 0, 0, 0);\
                        acc[p][sr][sc] = __builtin_amdgcn_mfma_f32_16x16x32_f16(ah, bl[sc], acc[p][sr][sc], 0, 0, 0);\
                    }                                                          \
                }                                                              \
            }                                                                  \
        }                                                                      \
    }

    // ---- prologue: tile 0 staged; tile 1 loads in flight ----
    STAGE_LOAD(0, rbvA, raA1, raA2);
    STAGE_WRITE(0, rbvA, raA1, raA2);
    STAGE_LOAD(1, rbvB, raB1, raB2);
    __syncthreads();

    // ---- k-loop: manually unrolled x2 (static register-set selection) ----
    for (int kt = 0; kt < NKS; kt += 2) {
        // even step kt: B holds kt+1; A free -> load kt+2
        if (kt + 2 < NKS) STAGE_LOAD(kt + 2, rbvA, raA1, raA2);
        COMPUTE();
        __syncthreads();                          // reads of tile kt done
        if (kt + 1 < NKS) STAGE_WRITE(kt + 1, rbvB, raB1, raB2);
        __syncthreads();                          // tile kt+1 visible

        // odd step kt+1: A holds kt+2; B free -> load kt+3
        if (kt + 1 < NKS) {
            if (kt + 3 < NKS) STAGE_LOAD(kt + 3, rbvB, raB1, raB2);
            COMPUTE();
            __syncthreads();                      // reads of tile kt+1 done
            if (kt + 2 < NKS) STAGE_WRITE(kt + 2, rbvA, raA1, raA2);
            __syncthreads();                      // tile kt+2 visible
        }
    }
    #undef STAGE_LOAD
    #undef STAGE_WRITE
    #undef COMPUTE

    // ---- epilogue: per row-tile, acc -> P (overlays arena) -> partial logits
    const int ug   = tid >> 4;          // 0..31
    const int td16 = tid & 15;
    float4 w0 = ld4(&w2s_l[td16 * 8]);
    float4 w1v = ld4(&w2s_l[td16 * 8 + 4]);

    for (int rt = 0; rt < 4; ++rt) {
        if (rt < NRT) {
            __syncthreads();
            if ((rt & 1) == rg) {
                const int p = rt >> 1;
                #pragma unroll
                for (int sr = 0; sr < 2; ++sr)
                    #pragma unroll
                    for (int sc = 0; sc < 2; ++sc)
                        #pragma unroll
                        for (int jj = 0; jj < 4; ++jj)
                            Pl[(sr * 16 + gb * 4 + jj) * PSS + cg * 32 + sc * 16 + r16] =
                                acc[p][sr][sc][jj];
            }
            __syncthreads();
            const int u = rt * 32 + ug;
            if (u < U) {
                float4 p0 = ld4(&Pl[ug * PSS + td16 * 8]);
                float4 p1 = ld4(&Pl[ug * PSS + td16 * 8 + 4]);
                int n = head_l[u];
                while (n >= 0) {
                    const float* bp = b1 + (size_t)n * DD + h * EH + td16 * 8;
                    float4 b0 = ld4(bp);
                    float4 b1v = ld4(bp + 4);
                    float s = fmaxf(p0.x + b0.x,  0.f) * w0.x
                            + fmaxf(p0.y + b0.y,  0.f) * w0.y
                            + fmaxf(p0.z + b0.z,  0.f) * w0.z
                            + fmaxf(p0.w + b0.w,  0.f) * w0.w
                            + fmaxf(p1.x + b1v.x, 0.f) * w1v.x
                            + fmaxf(p1.y + b1v.y, 0.f) * w1v.y
                            + fmaxf(p1.z + b1v.z, 0.f) * w1v.z
                            + fmaxf(p1.w + b1v.w, 0.f) * w1v.w;
                    #pragma unroll
                    for (int m = 8; m >= 1; m >>= 1) s += __shfl_xor(s, m, 16);
                    if (td16 == 0) part[(size_t)b * 256 + h * NN + n] = s;
                    n = next_l[n];
                }
            }
        }
    }
}

// ---------------------------------------------------------------------------
// Kernel 3: per drug — combine partials (+b2s), softmax, sparse ent gather
// ---------------------------------------------------------------------------
__global__ __launch_bounds__(256)
void gnn_gather(const float* __restrict__ drug_table,
                const float* __restrict__ ent_table,
                const int*   __restrict__ drug_name,
                const int*   __restrict__ adj_tail,
                const float* __restrict__ part,
                const float* __restrict__ b2s_g,
                float* __restrict__ xbuf)
{
    __shared__ float score_l[NN];
    __shared__ int   tail_l[NN];

    const int b = blockIdx.x, tid = threadIdx.x;

    if (tid < NN) {
        tail_l[tid]  = adj_tail[b * NN + tid];
        score_l[tid] = part[(size_t)b * 256 + tid]
                     + part[(size_t)b * 256 + NN + tid] + b2s_g[tid];
    }
    __syncthreads();

    if (tid < 64) {
        float l0 = score_l[tid], l1 = score_l[tid + 64];
        float M = fmaxf(l0, l1);
        #pragma unroll
        for (int m = 32; m >= 1; m >>= 1) M = fmaxf(M, __shfl_xor(M, m, 64));
        float e0 = expf(l0 - M), e1 = expf(l1 - M);
        float S = e0 + e1;
        #pragma unroll
        for (int m = 32; m >= 1; m >>= 1) S += __shfl_xor(S, m, 64);
        float inv = 1.f / S;
        score_l[tid]      = e0 * inv;
        score_l[tid + 64] = e1 * inv;
    }
    __syncthreads();

    // sparse gather (softmax ~one-hot; skipped mass < 1.3e-7)
    float w = 0.f;
    for (int n = 0; n < NN; ++n) {
        float s = score_l[n];
        if (s > 1e-9f)
            w = fmaf(s, ent_table[(size_t)tail_l[n] * DD + tid], w);
    }
    xbuf[(size_t)b * 512 + tid]       = w;
    xbuf[(size_t)b * 512 + 256 + tid] = drug_table[(size_t)drug_name[b] * DD + tid];
}

// ---------------------------------------------------------------------------
// Kernel 4: batched linear
// ---------------------------------------------------------------------------
__global__ __launch_bounds__(256)
void gnn_lin(const float* __restrict__ lin_w,
             const float* __restrict__ lin_b,
             const float* __restrict__ xbuf,
             float* __restrict__ Y)
{
    __shared__ float x_l[LDRUGS * 512];

    const int g = blockIdx.x, tid = threadIdx.x;
    const int b0 = g * LDRUGS;

    #pragma unroll
    for (int i = 0; i < LDRUGS * 2; ++i) {
        int f = tid + i * 256;
        *reinterpret_cast<float4*>(&x_l[f * 4]) = ld4(&xbuf[(size_t)b0 * 512 + f * 4]);
    }
    __syncthreads();

    const float* lw = lin_w + (size_t)tid * 512;
    float dot[LDRUGS];
    #pragma unroll
    for (int d = 0; d < LDRUGS; ++d) dot[d] = 0.f;

    for (int k4 = 0; k4 < 128; ++k4) {
        float4 wv = ld4(&lw[k4 * 4]);
        #pragma unroll
        for (int d = 0; d < LDRUGS; ++d) {
            float4 xv = ld4(&x_l[d * 512 + k4 * 4]);
            dot[d] += wv.x * xv.x + wv.y * xv.y + wv.z * xv.z + wv.w * xv.w;
        }
    }

    const float bb = lin_b[tid];
    #pragma unroll
    for (int d = 0; d < LDRUGS; ++d) {
        if (b0 + d < NB)
            Y[(size_t)(b0 + d) * DD + tid] = fmaxf(dot[d] + bb, 0.f);
    }
}

// ---------------------------------------------------------------------------
// Kernel 5: BN stats (deterministic fixed-order reduction) + apply
// ---------------------------------------------------------------------------
__global__ void bn_stats(const float* __restrict__ Y, float* __restrict__ stats)
{
    int d = blockIdx.x, t = threadIdx.x;   // 256 blocks x 64 threads
    float s = 0.f, ss = 0.f;
    for (int b = t; b < NB; b += 64) {
        float v = Y[(size_t)b * DD + d];
        s += v; ss += v * v;
    }
    #pragma unroll
    for (int m = 32; m >= 1; m >>= 1) {
        s  += __shfl_xor(s, m, 64);
        ss += __shfl_xor(ss, m, 64);
    }
    if (t == 0) {
        float mean = s * (1.f / NB);
        float var  = ss * (1.f / NB) - mean * mean;
        stats[d]      = mean;
        stats[DD + d] = rsqrtf(var + 1e-5f);
    }
}

__global__ void bn_apply(float* __restrict__ Y, const float* __restrict__ stats,
                         const float* __restrict__ gamma, const float* __restrict__ beta)
{
    int b = blockIdx.x, t = threadIdx.x;
    float mean = stats[t], inv = stats[DD + t];
    float v = Y[(size_t)b * DD + t];
    Y[(size_t)b * DD + t] = gamma[t] * (v - mean) * inv + beta[t];
}

extern "C" void kernel_launch(void* const* d_in, const int* in_sizes, int n_in,
                              void* d_out, int out_size, void* d_ws, size_t ws_size,
                              hipStream_t stream)
{
    const float* drug_table = (const float*)d_in[0];
    const float* rela_table = (const float*)d_in[1];
    const float* ent_table  = (const float*)d_in[2];
    const float* W1         = (const float*)d_in[3];
    const float* b1         = (const float*)d_in[4];
    const float* W2         = (const float*)d_in[5];
    const float* b2         = (const float*)d_in[6];
    const float* lin_w      = (const float*)d_in[7];
    const float* lin_b      = (const float*)d_in[8];
    const float* bn_g       = (const float*)d_in[9];
    const float* bn_b       = (const float*)d_in[10];
    const int*   drug_name  = (const int*)d_in[11];
    const int*   adj_tail   = (const int*)d_in[12];
    const int*   adj_rel    = (const int*)d_in[13];
    float* out = (float*)d_out;

    const int NBP = ((NB + LDRUGS - 1) / LDRUGS) * LDRUGS;   // 576
    float* w2s   = (float*)d_ws;                   // NB*DD
    float* b2s   = w2s + (size_t)NB * DD;          // NN
    float* part  = b2s + NN;                       // NB*256
    float* xbuf  = part + (size_t)NB * 256;        // NBP*512
    float* stats = xbuf + (size_t)NBP * 512;       // 2*DD

    sum_rows<<<2 * NB + 1, 256, 0, stream>>>(W2, b2, w2s, b2s);
    gnn_mm<<<2 * NB, 512, 0, stream>>>(drug_table, rela_table, W1, b1,
                                       drug_name, adj_rel, w2s, part);
    gnn_gather<<<NB, 256, 0, stream>>>(drug_table, ent_table, drug_name,
                                       adj_tail, part, b2s, xbuf);
    gnn_lin<<<NBP / LDRUGS, 256, 0, stream>>>(lin_w, lin_b, xbuf, out);
    bn_stats<<<DD, 64, 0, stream>>>(out, stats);
    bn_apply<<<NB, DD, 0, stream>>>(out, stats, bn_g, bn_b);
}